// Round 5
// baseline (409.976 us; speedup 1.0000x reference)
//
#include <hip/hip_runtime.h>
#include <hip/hip_bf16.h>
#include <cstddef>

#define NP1 6001
#define BLn 6400
#define TRI 20100   // 200*201/2 causal pairs per batch

__global__ __launch_bounds__(256) void k_mark(const int* logs, int* used) {
    int i = blockIdx.x * 256 + threadIdx.x;
    if (i < BLn) used[logs[i]] = 1;
}

// used=0 init folded in; h_item = item_emb @ W_item ; wh1 = h@a[:64] ; wh2 = h@a[64:]
// 8 rows/block (2 per wave, interleaved ILP). Grid 751.
__global__ __launch_bounds__(256) void k_hitem(const float* emb, const float* Wi,
                                               const float* a_item,
                                               float* h, float* wh1, float* wh2, int* used) {
    __shared__ float Wl[4096];
    int tid = threadIdx.x;
    int gid = blockIdx.x * 256 + tid;
    if (gid < NP1) used[gid] = 0;
    {
        const float4* w4 = (const float4*)Wi;
        float4* l4 = (float4*)Wl;
        for (int i = tid; i < 1024; i += 256) l4[i] = w4[i];
    }
    __syncthreads();
    int wave = tid >> 6, lane = tid & 63;
    int rA = blockIdx.x * 8 + wave * 2;
    int rB = rA + 1;
    bool vA = rA < NP1, vB = rB < NP1;
    if (!vA) return;
    float eA = emb[(size_t)rA * 64 + lane];
    float eB = vB ? emb[(size_t)rB * 64 + lane] : 0.f;
    float aA = 0.f, aB = 0.f;
    #pragma unroll
    for (int k = 0; k < 64; k++) {
        float wv = Wl[k * 64 + lane];
        aA += __shfl(eA, k, 64) * wv;
        aB += __shfl(eB, k, 64) * wv;
    }
    h[(size_t)rA * 64 + lane] = aA;
    if (vB) h[(size_t)rB * 64 + lane] = aB;
    float p1A = aA * a_item[lane];
    float p2A = aA * a_item[64 + lane];
    float p1B = aB * a_item[lane];
    float p2B = aB * a_item[64 + lane];
    for (int off = 32; off > 0; off >>= 1) {
        p1A += __shfl_down(p1A, off, 64);
        p2A += __shfl_down(p2A, off, 64);
        p1B += __shfl_down(p1B, off, 64);
        p2B += __shfl_down(p2B, off, 64);
    }
    if (lane == 0) {
        wh1[rA] = p1A; wh2[rA] = p2A;
        if (vB) { wh1[rB] = p1B; wh2[rB] = p2B; }
    }
}

#define MAXNZ 1024
// one block per adjacency row. Pass 1: tight (j,a) compaction scan (pure stream).
// Pass 2: leaky+exp+sum over ~60 compacted nonzeros (inputs ~0.1-scale => |e|<<1,
// softmax safe without max-subtraction). Pass 3: two sparse matvecs.
__global__ __launch_bounds__(256) void k_gat(const float* adj, const float* h,
                                             const float* wh1, const float* wh2,
                                             const int* used, float* gat, float* trans) {
    int row = blockIdx.x;
    if (!used[row]) return;
    __shared__ int s_j[MAXNZ];
    __shared__ float s_a[MAXNZ];
    __shared__ float s_e[MAXNZ];   // exp(e)
    __shared__ int s_cnt;
    __shared__ float s_part[4];
    __shared__ float s_g[4][64];
    __shared__ float s_t[4][64];
    int tid = threadIdx.x;
    if (tid == 0) s_cnt = 0;
    __syncthreads();
    const float* arow = adj + (size_t)row * NP1;

    // row byte alignment: (row*6001) % 4 == row % 4 elements
    int j0 = (4 - (row & 3)) & 3;
    int nv = (NP1 - j0) >> 2;

    for (int j = tid; j < j0; j += 256) {
        float a = arow[j];
        if (a > 0.f) {
            int pos = atomicAdd(&s_cnt, 1);
            if (pos < MAXNZ) { s_j[pos] = j; s_a[pos] = a; }
        }
    }
    const float4* av = (const float4*)(arow + j0);
    for (int v = tid; v < nv; v += 256) {
        float4 a4 = av[v];
        int jb = j0 + 4 * v;
        if (a4.x > 0.f) { int pos = atomicAdd(&s_cnt, 1); if (pos < MAXNZ) { s_j[pos] = jb;     s_a[pos] = a4.x; } }
        if (a4.y > 0.f) { int pos = atomicAdd(&s_cnt, 1); if (pos < MAXNZ) { s_j[pos] = jb + 1; s_a[pos] = a4.y; } }
        if (a4.z > 0.f) { int pos = atomicAdd(&s_cnt, 1); if (pos < MAXNZ) { s_j[pos] = jb + 2; s_a[pos] = a4.z; } }
        if (a4.w > 0.f) { int pos = atomicAdd(&s_cnt, 1); if (pos < MAXNZ) { s_j[pos] = jb + 3; s_a[pos] = a4.w; } }
    }
    for (int j = j0 + 4 * nv + tid; j < NP1; j += 256) {
        float a = arow[j];
        if (a > 0.f) {
            int pos = atomicAdd(&s_cnt, 1);
            if (pos < MAXNZ) { s_j[pos] = j; s_a[pos] = a; }
        }
    }
    __syncthreads();
    int cnt = min(s_cnt, MAXNZ);
    float w1 = wh1[row];
    float ssum = 0.f;
    for (int i = tid; i < cnt; i += 256) {
        float e = w1 + wh2[s_j[i]];
        e = e > 0.f ? e : 0.01f * e;
        float ee = __expf(e);
        s_e[i] = ee;
        ssum += ee;
    }
    int lane = tid & 63, g = tid >> 6;
    for (int o = 32; o > 0; o >>= 1) ssum += __shfl_xor(ssum, o, 64);
    if (lane == 0) s_part[g] = ssum;
    __syncthreads();
    float inv = __builtin_amdgcn_rcpf(s_part[0] + s_part[1] + s_part[2] + s_part[3]);
    float gacc = 0.f, tacc = 0.f;
    for (int i = g; i < cnt; i += 4) {
        int j = s_j[i];
        float hv = h[(size_t)j * 64 + lane];
        gacc += s_e[i] * hv;
        tacc += s_a[i] * hv;
    }
    s_g[g][lane] = gacc * inv;
    s_t[g][lane] = tacc;
    __syncthreads();
    if (g == 0) {
        gat[(size_t)row * 64 + lane]   = s_g[0][lane] + s_g[1][lane] + s_g[2][lane] + s_g[3][lane];
        trans[(size_t)row * 64 + lane] = s_t[0][lane] + s_t[1][lane] + s_t[2][lane] + s_t[3][lane];
    }
}

// seqs = coff*gat + (1-coff)*trans + self ; M1 = seqs_pos@W1 ; M2T[b][d][l] = (seqs_pos@W2)[d]
// 512 threads, full LDS staging, 2 positions/wave interleaved.
__global__ __launch_bounds__(512) void k_seq(const int* logs, const float* gat, const float* trans,
                                             const float* emb, const float* posemb,
                                             const float* cc_, const float* cn_,
                                             const float* W1_, const float* W2_,
                                             float* seqs, float* M1, float* M2T) {
    __shared__ float cc[4096], cn[4096], W1[4096], W2[4096];
    int tid = threadIdx.x;
    {
        float4* c4 = (float4*)cc; float4* n4 = (float4*)cn;
        float4* w14 = (float4*)W1; float4* w24 = (float4*)W2;
        const float4* sc = (const float4*)cc_; const float4* sn = (const float4*)cn_;
        const float4* s1 = (const float4*)W1_; const float4* s2 = (const float4*)W2_;
        for (int i = tid; i < 1024; i += 512) {
            c4[i] = sc[i]; n4[i] = sn[i]; w14[i] = s1[i]; w24[i] = s2[i];
        }
    }
    __syncthreads();
    int wave = tid >> 6, lane = tid & 63;
    int pA = blockIdx.x * 16 + wave * 2;     // grid 400 -> 6400 positions
    int pB = pA + 1;
    int bA = pA / 200, lA = pA - bA * 200;
    int bB = pB / 200, lB = pB - bB * 200;
    int nA = logs[pA], nB = logs[pB];
    float gA = gat[(size_t)nA * 64 + lane];
    float gB = gat[(size_t)nB * 64 + lane];
    float tA = trans[(size_t)nA * 64 + lane];
    float tB = trans[(size_t)nB * 64 + lane];
    float seA = emb[(size_t)nA * 64 + lane];
    float seB = emb[(size_t)nB * 64 + lane];
    float ciA = 0.f, ciB = 0.f;
    #pragma unroll
    for (int k = 0; k < 64; k++) {
        float ccv = cc[k * 64 + lane], cnv = cn[k * 64 + lane];
        ciA += __shfl(gA, k, 64) * ccv + __shfl(tA, k, 64) * cnv;
        ciB += __shfl(gB, k, 64) * ccv + __shfl(tB, k, 64) * cnv;
    }
    float coA = 1.f / (1.f + __expf(-ciA));
    float coB = 1.f / (1.f + __expf(-ciB));
    float sA = coA * gA + (1.f - coA) * tA + seA;
    float sB = coB * gB + (1.f - coB) * tB + seB;
    seqs[(size_t)pA * 64 + lane] = sA;
    seqs[(size_t)pB * 64 + lane] = sB;
    float spA = sA + (nA != 0 ? posemb[lA * 64 + lane] : 0.f);
    float spB = sB + (nB != 0 ? posemb[lB * 64 + lane] : 0.f);
    float m1A = 0.f, m2A = 0.f, m1B = 0.f, m2B = 0.f;
    #pragma unroll
    for (int k = 0; k < 64; k++) {
        float w1v = W1[k * 64 + lane], w2v = W2[k * 64 + lane];
        float skA = __shfl(spA, k, 64), skB = __shfl(spB, k, 64);
        m1A += skA * w1v; m2A += skA * w2v;
        m1B += skB * w1v; m2B += skB * w2v;
    }
    M1[(size_t)pA * 64 + lane] = m1A;
    M1[(size_t)pB * 64 + lane] = m1B;
    M2T[((size_t)bA * 64 + lane) * 200 + lA] = m2A;
    M2T[((size_t)bB * 64 + lane) * 200 + lB] = m2B;
}

// score[b,q,k] = sum_d sigmoid(M1[b,q,d]+M2[b,k,d]) * b_attn[d]; causal triples only.
// R11 lesson (from R10's k_sff): keep this standalone — the flat idx->triangle map
// gives even distribution over 643K threads; fusing it behind per-block barriers
// serialized the triangular imbalance (150us kernel).
__global__ __launch_bounds__(256) void k_score(const float* M1, const float* M2T,
                                               const float* battn, float* score) {
    __shared__ float bv[64];
    int tid = threadIdx.x;
    if (tid < 64) bv[tid] = battn[tid];
    __syncthreads();
    int idx = blockIdx.x * 256 + tid;          // grid 2513 -> 643,328 (need 643,200)
    if (idx >= TRI * 32) return;
    int b = idx / TRI;
    int t = idx - b * TRI;
    int q = (int)((sqrtf(8.0f * (float)t + 1.0f) - 1.0f) * 0.5f);
    while ((q + 1) * (q + 2) / 2 <= t) q++;
    while (q * (q + 1) / 2 > t) q--;
    int k = t - q * (q + 1) / 2;
    const float4* m14 = (const float4*)(M1 + ((size_t)(b * 200 + q)) * 64);
    const float* m2 = M2T + (size_t)b * 12800 + k;
    float s0 = 0.f, s1 = 0.f, s2 = 0.f, s3 = 0.f;
    #pragma unroll
    for (int d4 = 0; d4 < 16; d4++) {
        float4 mv = m14[d4];
        int d = d4 * 4;
        float x0 = mv.x + m2[(size_t)(d + 0) * 200];
        float x1 = mv.y + m2[(size_t)(d + 1) * 200];
        float x2 = mv.z + m2[(size_t)(d + 2) * 200];
        float x3 = mv.w + m2[(size_t)(d + 3) * 200];
        s0 += bv[d + 0] * __builtin_amdgcn_rcpf(1.0f + __expf(-x0));
        s1 += bv[d + 1] * __builtin_amdgcn_rcpf(1.0f + __expf(-x1));
        s2 += bv[d + 2] * __builtin_amdgcn_rcpf(1.0f + __expf(-x2));
        s3 += bv[d + 3] * __builtin_amdgcn_rcpf(1.0f + __expf(-x3));
    }
    score[((size_t)(b * 200 + q)) * 200 + k] = (s0 + s1) + (s2 + s3);
}

// R11: fused score@seqs + FFN/UpDown/logits (the BALANCED half of R10's fusion —
// score stays split). Block = (batch b, 8 consecutive q), grid 800, 256 threads.
// 64KB LDS arena time-shared: phase A = s_seq[12800] (51.2KB, seqs[b] prefix);
// phase B (after barrier, s_seq dead) = c1w|c2w|dw weights (64KB).
// Phase 1: wave w contracts score rows 2w,2w+1 with s_seq -> fin in REGISTERS
//   (2-way LDS bank aliasing = free; score rows read float4 from global/L2).
// Phase 2: FFN tail, 2 positions/wave interleaved (shares every weight read).
// Kills the fin round-trip + 1 launch. VGPR ~144, no spill (proven in R10 k_sff).
__global__ __launch_bounds__(256) void k_fffn(const float* score, const float* seqs,
                                              const int* poss, const int* negs,
                                              const float* emb,
                                              const float* c1w, const float* c1b,
                                              const float* c2w, const float* c2b,
                                              const float* upw, const float* upb,
                                              const float* gw, const float* gb,
                                              const float* dw, const float* db,
                                              float* out) {
    __shared__ __align__(16) float lds[16384];
    int tid = threadIdx.x;
    int B = blockIdx.x;
    int b = B / 25;
    int qbase = (B - b * 25) * 8;

    // ---- stage seqs[b][0..qbase+7] ----
    {
        int n4 = (qbase + 8) * 16;
        const float4* src4 = (const float4*)(seqs + (size_t)b * 12800);
        float4* d4 = (float4*)lds;
        for (int i = tid; i < n4; i += 256) d4[i] = src4[i];
    }
    __syncthreads();

    // ---- phase 1: fin = score_row @ s_seq (stays in registers) ----
    int wave = tid >> 6, lane = tid & 63;
    int qA = qbase + wave * 2, qB = qA + 1;
    const float* srA = score + ((size_t)b * 200 + qA) * 200;
    const float* srB = srA + 200;
    float a0 = 0.f, a1 = 0.f, a2 = 0.f, a3 = 0.f;
    float c0 = 0.f, c1 = 0.f, c2 = 0.f, c3 = 0.f;
    int k = 0;
    #pragma unroll 2
    for (; k + 3 <= qA; k += 4) {
        float4 sa = *(const float4*)(srA + k);
        float4 sb = *(const float4*)(srB + k);
        float v0 = lds[(k + 0) * 64 + lane];
        float v1 = lds[(k + 1) * 64 + lane];
        float v2 = lds[(k + 2) * 64 + lane];
        float v3 = lds[(k + 3) * 64 + lane];
        a0 += sa.x * v0; a1 += sa.y * v1; a2 += sa.z * v2; a3 += sa.w * v3;
        c0 += sb.x * v0; c1 += sb.y * v1; c2 += sb.z * v2; c3 += sb.w * v3;
    }
    for (; k <= qA; k++) {
        float v = lds[k * 64 + lane];
        a0 += srA[k] * v;
        c0 += srB[k] * v;
    }
    c1 += srB[qB] * lds[qB * 64 + lane];
    float xA = (a0 + a1) + (a2 + a3);
    float xB = (c0 + c1) + (c2 + c3);
    __syncthreads();   // all phase-1 reads of s_seq done

    // ---- phase 2: weights over the dead arena, then FFN tail ----
    {
        float4* l4 = (float4*)lds;
        const float4* a4 = (const float4*)c1w;
        const float4* b4 = (const float4*)c2w;
        const float4* d4 = (const float4*)dw;
        for (int i = tid; i < 1024; i += 256) l4[i] = a4[i];
        for (int i = tid; i < 1024; i += 256) l4[1024 + i] = b4[i];
        for (int i = tid; i < 2048; i += 256) l4[2048 + i] = d4[i];
    }
    __syncthreads();

    float accA = c1b[lane], accB = c1b[lane];
    #pragma unroll
    for (int kk = 0; kk < 64; kk++) {
        float wv = lds[kk * 64 + lane];
        accA += __shfl(xA, kk, 64) * wv;
        accB += __shfl(xB, kk, 64) * wv;
    }
    float h1A = accA > 0.f ? accA : 0.f;
    float h1B = accB > 0.f ? accB : 0.f;
    accA = c2b[lane]; accB = c2b[lane];
    #pragma unroll
    for (int kk = 0; kk < 64; kk++) {
        float wv = lds[4096 + kk * 64 + lane];
        accA += __shfl(h1A, kk, 64) * wv;
        accB += __shfl(h1B, kk, 64) * wv;
    }
    float x2A = xA + accA;
    float x2B = xB + accB;
    // ---- UpDown ----
    float u0A = upb[lane], u1A = upb[64 + lane];
    float g0A = gb[lane],  g1A = gb[64 + lane];
    float u0B = u0A, u1B = u1A, g0B = g0A, g1B = g1A;
    #pragma unroll
    for (int kk = 0; kk < 64; kk++) {
        float up0 = upw[kk * 128 + lane];
        float up1 = upw[kk * 128 + 64 + lane];
        float gv0 = gw[kk * 128 + lane];
        float gv1 = gw[kk * 128 + 64 + lane];
        float xkA = __shfl(x2A, kk, 64), xkB = __shfl(x2B, kk, 64);
        u0A += xkA * up0; u1A += xkA * up1; g0A += xkA * gv0; g1A += xkA * gv1;
        u0B += xkB * up0; u1B += xkB * up1; g0B += xkB * gv0; g1B += xkB * gv1;
    }
    g0A = g0A > 0.f ? g0A : 0.f;  g1A = g1A > 0.f ? g1A : 0.f;
    g0B = g0B > 0.f ? g0B : 0.f;  g1B = g1B > 0.f ? g1B : 0.f;
    float hh0A = g0A * u0A, hh1A = g1A * u1A;
    float hh0B = g0B * u0B, hh1B = g1B * u1B;
    accA = db[lane]; accB = db[lane];
    #pragma unroll
    for (int kk = 0; kk < 64; kk++) {
        float wv = lds[8192 + kk * 64 + lane];
        accA += __shfl(hh0A, kk, 64) * wv;
        accB += __shfl(hh0B, kk, 64) * wv;
    }
    #pragma unroll
    for (int kk = 0; kk < 64; kk++) {
        float wv = lds[8192 + (64 + kk) * 64 + lane];
        accA += __shfl(hh1A, kk, 64) * wv;
        accB += __shfl(hh1B, kk, 64) * wv;
    }
    float x3A = x2A + (accA > 0.f ? accA : 0.f);
    float x3B = x2B + (accB > 0.f ? accB : 0.f);
    // ---- logits ----
    int pA = b * 200 + qA, pB = pA + 1;
    int pnA = poss[pA], nnA = negs[pA];
    int pnB = poss[pB], nnB = negs[pB];
    float plA = x3A * emb[(size_t)pnA * 64 + lane];
    float nlA = x3A * emb[(size_t)nnA * 64 + lane];
    float plB = x3B * emb[(size_t)pnB * 64 + lane];
    float nlB = x3B * emb[(size_t)nnB * 64 + lane];
    for (int o = 32; o > 0; o >>= 1) {
        plA += __shfl_xor(plA, o, 64);
        nlA += __shfl_xor(nlA, o, 64);
        plB += __shfl_xor(plB, o, 64);
        nlB += __shfl_xor(nlB, o, 64);
    }
    if (lane == 0) {
        out[pA] = plA; out[BLn + pA] = nlA;
        out[pB] = plB; out[BLn + pB] = nlB;
    }
}

extern "C" void kernel_launch(void* const* d_in, const int* in_sizes, int n_in,
                              void* d_out, int out_size, void* d_ws, size_t ws_size,
                              hipStream_t stream) {
    const int* logs = (const int*)d_in[0];
    const int* poss = (const int*)d_in[1];
    const int* negs = (const int*)d_in[2];
    const float* adj      = (const float*)d_in[4];
    const float* item_emb = (const float*)d_in[5];
    const float* posemb   = (const float*)d_in[6];
    const float* W_item   = (const float*)d_in[7];
    const float* a_item   = (const float*)d_in[8];
    const float* W_1      = (const float*)d_in[9];
    const float* W_2      = (const float*)d_in[10];
    const float* b_attn   = (const float*)d_in[11];
    const float* cc       = (const float*)d_in[12];
    const float* cn       = (const float*)d_in[13];
    const float* c1w      = (const float*)d_in[14];
    const float* c1b      = (const float*)d_in[15];
    const float* c2w      = (const float*)d_in[16];
    const float* c2b      = (const float*)d_in[17];
    const float* upw      = (const float*)d_in[18];
    const float* upb      = (const float*)d_in[19];
    const float* gw       = (const float*)d_in[20];
    const float* gb       = (const float*)d_in[21];
    const float* dw       = (const float*)d_in[22];
    const float* db       = (const float*)d_in[23];
    float* out = (float*)d_out;

    float* W = (float*)d_ws;
    size_t off = 0;
    float* h_item = W + off; off += 384064;   // 6001*64
    float* wh1    = W + off; off += 6016;
    float* wh2    = W + off; off += 6016;
    int*   used   = (int*)(W + off); off += 6016;
    float* gat    = W + off; off += 384064;
    float* trans  = W + off; off += 384064;
    float* seqs   = W + off; off += 409600;   // 6400*64
    float* M1     = W + off; off += 409600;
    float* M2T    = W + off; off += 409600;   // [32][64][200]
    float* score  = W + off; off += 1280000;  // [32][200][200]

    k_hitem <<<751, 256, 0, stream>>>(item_emb, W_item, a_item, h_item, wh1, wh2, used);
    k_mark  <<<25, 256, 0, stream>>>(logs, used);
    k_gat   <<<6001, 256, 0, stream>>>(adj, h_item, wh1, wh2, used, gat, trans);
    k_seq   <<<400, 512, 0, stream>>>(logs, gat, trans, item_emb, posemb, cc, cn, W_1, W_2,
                                      seqs, M1, M2T);
    k_score <<<2513, 256, 0, stream>>>(M1, M2T, b_attn, score);
    k_fffn  <<<800, 256, 0, stream>>>(score, seqs, poss, negs, item_emb,
                                      c1w, c1b, c2w, c2b, upw, upb, gw, gb, dw, db, out);
}

// Round 6
// 405.792 us; speedup vs baseline: 1.0103x; 1.0103x over previous
//
#include <hip/hip_runtime.h>
#include <hip/hip_bf16.h>
#include <cstddef>

#define NP1 6001
#define BLn 6400
#define TRI 20100   // 200*201/2 causal pairs per batch

__global__ __launch_bounds__(256) void k_mark(const int* logs, int* used) {
    int i = blockIdx.x * 256 + threadIdx.x;
    if (i < BLn) used[logs[i]] = 1;
}

// used=0 init folded in; h_item = item_emb @ W_item ; wh1 = h@a[:64] ; wh2 = h@a[64:]
// 8 rows/block (2 per wave, interleaved ILP). Grid 751.
__global__ __launch_bounds__(256) void k_hitem(const float* emb, const float* Wi,
                                               const float* a_item,
                                               float* h, float* wh1, float* wh2, int* used) {
    __shared__ float Wl[4096];
    int tid = threadIdx.x;
    int gid = blockIdx.x * 256 + tid;
    if (gid < NP1) used[gid] = 0;
    {
        const float4* w4 = (const float4*)Wi;
        float4* l4 = (float4*)Wl;
        for (int i = tid; i < 1024; i += 256) l4[i] = w4[i];
    }
    __syncthreads();
    int wave = tid >> 6, lane = tid & 63;
    int rA = blockIdx.x * 8 + wave * 2;
    int rB = rA + 1;
    bool vA = rA < NP1, vB = rB < NP1;
    if (!vA) return;
    float eA = emb[(size_t)rA * 64 + lane];
    float eB = vB ? emb[(size_t)rB * 64 + lane] : 0.f;
    float aA = 0.f, aB = 0.f;
    #pragma unroll
    for (int k = 0; k < 64; k++) {
        float wv = Wl[k * 64 + lane];
        aA += __shfl(eA, k, 64) * wv;
        aB += __shfl(eB, k, 64) * wv;
    }
    h[(size_t)rA * 64 + lane] = aA;
    if (vB) h[(size_t)rB * 64 + lane] = aB;
    float p1A = aA * a_item[lane];
    float p2A = aA * a_item[64 + lane];
    float p1B = aB * a_item[lane];
    float p2B = aB * a_item[64 + lane];
    for (int off = 32; off > 0; off >>= 1) {
        p1A += __shfl_down(p1A, off, 64);
        p2A += __shfl_down(p2A, off, 64);
        p1B += __shfl_down(p1B, off, 64);
        p2B += __shfl_down(p2B, off, 64);
    }
    if (lane == 0) {
        wh1[rA] = p1A; wh2[rA] = p2A;
        if (vB) { wh1[rB] = p1B; wh2[rB] = p2B; }
    }
}

#define MAXNZ 1024
// one block per adjacency row. Pass 1: tight (j,a) compaction scan (pure stream).
// Pass 2: leaky+exp+sum over ~60 compacted nonzeros (inputs ~0.1-scale => |e|<<1,
// softmax safe without max-subtraction). Pass 3: two sparse matvecs.
__global__ __launch_bounds__(256) void k_gat(const float* adj, const float* h,
                                             const float* wh1, const float* wh2,
                                             const int* used, float* gat, float* trans) {
    int row = blockIdx.x;
    if (!used[row]) return;
    __shared__ int s_j[MAXNZ];
    __shared__ float s_a[MAXNZ];
    __shared__ float s_e[MAXNZ];   // exp(e)
    __shared__ int s_cnt;
    __shared__ float s_part[4];
    __shared__ float s_g[4][64];
    __shared__ float s_t[4][64];
    int tid = threadIdx.x;
    if (tid == 0) s_cnt = 0;
    __syncthreads();
    const float* arow = adj + (size_t)row * NP1;

    // row byte alignment: (row*6001) % 4 == row % 4 elements
    int j0 = (4 - (row & 3)) & 3;
    int nv = (NP1 - j0) >> 2;

    for (int j = tid; j < j0; j += 256) {
        float a = arow[j];
        if (a > 0.f) {
            int pos = atomicAdd(&s_cnt, 1);
            if (pos < MAXNZ) { s_j[pos] = j; s_a[pos] = a; }
        }
    }
    const float4* av = (const float4*)(arow + j0);
    for (int v = tid; v < nv; v += 256) {
        float4 a4 = av[v];
        int jb = j0 + 4 * v;
        if (a4.x > 0.f) { int pos = atomicAdd(&s_cnt, 1); if (pos < MAXNZ) { s_j[pos] = jb;     s_a[pos] = a4.x; } }
        if (a4.y > 0.f) { int pos = atomicAdd(&s_cnt, 1); if (pos < MAXNZ) { s_j[pos] = jb + 1; s_a[pos] = a4.y; } }
        if (a4.z > 0.f) { int pos = atomicAdd(&s_cnt, 1); if (pos < MAXNZ) { s_j[pos] = jb + 2; s_a[pos] = a4.z; } }
        if (a4.w > 0.f) { int pos = atomicAdd(&s_cnt, 1); if (pos < MAXNZ) { s_j[pos] = jb + 3; s_a[pos] = a4.w; } }
    }
    for (int j = j0 + 4 * nv + tid; j < NP1; j += 256) {
        float a = arow[j];
        if (a > 0.f) {
            int pos = atomicAdd(&s_cnt, 1);
            if (pos < MAXNZ) { s_j[pos] = j; s_a[pos] = a; }
        }
    }
    __syncthreads();
    int cnt = min(s_cnt, MAXNZ);
    float w1 = wh1[row];
    float ssum = 0.f;
    for (int i = tid; i < cnt; i += 256) {
        float e = w1 + wh2[s_j[i]];
        e = e > 0.f ? e : 0.01f * e;
        float ee = __expf(e);
        s_e[i] = ee;
        ssum += ee;
    }
    int lane = tid & 63, g = tid >> 6;
    for (int o = 32; o > 0; o >>= 1) ssum += __shfl_xor(ssum, o, 64);
    if (lane == 0) s_part[g] = ssum;
    __syncthreads();
    float inv = __builtin_amdgcn_rcpf(s_part[0] + s_part[1] + s_part[2] + s_part[3]);
    float gacc = 0.f, tacc = 0.f;
    for (int i = g; i < cnt; i += 4) {
        int j = s_j[i];
        float hv = h[(size_t)j * 64 + lane];
        gacc += s_e[i] * hv;
        tacc += s_a[i] * hv;
    }
    s_g[g][lane] = gacc * inv;
    s_t[g][lane] = tacc;
    __syncthreads();
    if (g == 0) {
        gat[(size_t)row * 64 + lane]   = s_g[0][lane] + s_g[1][lane] + s_g[2][lane] + s_g[3][lane];
        trans[(size_t)row * 64 + lane] = s_t[0][lane] + s_t[1][lane] + s_t[2][lane] + s_t[3][lane];
    }
}

// seqs = coff*gat + (1-coff)*trans + self ; M1 = seqs_pos@W1 ; M2T[b][d][l] = (seqs_pos@W2)[d]
// 512 threads, full LDS staging, 2 positions/wave interleaved.
__global__ __launch_bounds__(512) void k_seq(const int* logs, const float* gat, const float* trans,
                                             const float* emb, const float* posemb,
                                             const float* cc_, const float* cn_,
                                             const float* W1_, const float* W2_,
                                             float* seqs, float* M1, float* M2T) {
    __shared__ float cc[4096], cn[4096], W1[4096], W2[4096];
    int tid = threadIdx.x;
    {
        float4* c4 = (float4*)cc; float4* n4 = (float4*)cn;
        float4* w14 = (float4*)W1; float4* w24 = (float4*)W2;
        const float4* sc = (const float4*)cc_; const float4* sn = (const float4*)cn_;
        const float4* s1 = (const float4*)W1_; const float4* s2 = (const float4*)W2_;
        for (int i = tid; i < 1024; i += 512) {
            c4[i] = sc[i]; n4[i] = sn[i]; w14[i] = s1[i]; w24[i] = s2[i];
        }
    }
    __syncthreads();
    int wave = tid >> 6, lane = tid & 63;
    int pA = blockIdx.x * 16 + wave * 2;     // grid 400 -> 6400 positions
    int pB = pA + 1;
    int bA = pA / 200, lA = pA - bA * 200;
    int bB = pB / 200, lB = pB - bB * 200;
    int nA = logs[pA], nB = logs[pB];
    float gA = gat[(size_t)nA * 64 + lane];
    float gB = gat[(size_t)nB * 64 + lane];
    float tA = trans[(size_t)nA * 64 + lane];
    float tB = trans[(size_t)nB * 64 + lane];
    float seA = emb[(size_t)nA * 64 + lane];
    float seB = emb[(size_t)nB * 64 + lane];
    float ciA = 0.f, ciB = 0.f;
    #pragma unroll
    for (int k = 0; k < 64; k++) {
        float ccv = cc[k * 64 + lane], cnv = cn[k * 64 + lane];
        ciA += __shfl(gA, k, 64) * ccv + __shfl(tA, k, 64) * cnv;
        ciB += __shfl(gB, k, 64) * ccv + __shfl(tB, k, 64) * cnv;
    }
    float coA = 1.f / (1.f + __expf(-ciA));
    float coB = 1.f / (1.f + __expf(-ciB));
    float sA = coA * gA + (1.f - coA) * tA + seA;
    float sB = coB * gB + (1.f - coB) * tB + seB;
    seqs[(size_t)pA * 64 + lane] = sA;
    seqs[(size_t)pB * 64 + lane] = sB;
    float spA = sA + (nA != 0 ? posemb[lA * 64 + lane] : 0.f);
    float spB = sB + (nB != 0 ? posemb[lB * 64 + lane] : 0.f);
    float m1A = 0.f, m2A = 0.f, m1B = 0.f, m2B = 0.f;
    #pragma unroll
    for (int k = 0; k < 64; k++) {
        float w1v = W1[k * 64 + lane], w2v = W2[k * 64 + lane];
        float skA = __shfl(spA, k, 64), skB = __shfl(spB, k, 64);
        m1A += skA * w1v; m2A += skA * w2v;
        m1B += skB * w1v; m2B += skB * w2v;
    }
    M1[(size_t)pA * 64 + lane] = m1A;
    M1[(size_t)pB * 64 + lane] = m1B;
    M2T[((size_t)bA * 64 + lane) * 200 + lA] = m2A;
    M2T[((size_t)bB * 64 + lane) * 200 + lB] = m2B;
}

// score[b,q,k] = sum_d sigmoid(M1[b,q,d]+M2[b,k,d]) * b_attn[d]; causal triples only.
// R10/R11 lesson: keep this standalone — the flat idx->triangle map distributes the
// triangular work evenly over 643K threads; any per-block fusion serializes it.
__global__ __launch_bounds__(256) void k_score(const float* M1, const float* M2T,
                                               const float* battn, float* score) {
    __shared__ float bv[64];
    int tid = threadIdx.x;
    if (tid < 64) bv[tid] = battn[tid];
    __syncthreads();
    int idx = blockIdx.x * 256 + tid;          // grid 2513 -> 643,328 (need 643,200)
    if (idx >= TRI * 32) return;
    int b = idx / TRI;
    int t = idx - b * TRI;
    int q = (int)((sqrtf(8.0f * (float)t + 1.0f) - 1.0f) * 0.5f);
    while ((q + 1) * (q + 2) / 2 <= t) q++;
    while (q * (q + 1) / 2 > t) q--;
    int k = t - q * (q + 1) / 2;
    const float4* m14 = (const float4*)(M1 + ((size_t)(b * 200 + q)) * 64);
    const float* m2 = M2T + (size_t)b * 12800 + k;
    float s0 = 0.f, s1 = 0.f, s2 = 0.f, s3 = 0.f;
    #pragma unroll
    for (int d4 = 0; d4 < 16; d4++) {
        float4 mv = m14[d4];
        int d = d4 * 4;
        float x0 = mv.x + m2[(size_t)(d + 0) * 200];
        float x1 = mv.y + m2[(size_t)(d + 1) * 200];
        float x2 = mv.z + m2[(size_t)(d + 2) * 200];
        float x3 = mv.w + m2[(size_t)(d + 3) * 200];
        s0 += bv[d + 0] * __builtin_amdgcn_rcpf(1.0f + __expf(-x0));
        s1 += bv[d + 1] * __builtin_amdgcn_rcpf(1.0f + __expf(-x1));
        s2 += bv[d + 2] * __builtin_amdgcn_rcpf(1.0f + __expf(-x2));
        s3 += bv[d + 3] * __builtin_amdgcn_rcpf(1.0f + __expf(-x3));
    }
    score[((size_t)(b * 200 + q)) * 200 + k] = (s0 + s1) + (s2 + s3);
}

// final[b,q,:] = sum_{k<=q} score[b,q,k] * seqs[b,k,:], seqs[b] prefix in LDS
// (51.2KB max -> 3 blocks/CU). Block = (batch b, 8 consecutive q), grid 800.
// Wave handles 2 adjacent q sharing every ds_read (2-way aliasing = free).
// Output into M1's slot (dead after k_score). R11 lesson: do NOT fuse the FFN tail
// behind this block's barrier (64KB arena -> 2 blocks/CU + triangular tail = 102us).
__global__ __launch_bounds__(256) void k_final(const float* score, const float* seqs,
                                               float* fin) {
    __shared__ float s_seq[12800];
    int tid = threadIdx.x;
    int B = blockIdx.x;
    int b = B / 25;
    int qbase = (B - b * 25) * 8;
    int kmax = qbase + 7;                      // rows 0..kmax of seqs[b] needed
    {
        int n4 = (kmax + 1) * 16;              // float4 count
        const float4* src4 = (const float4*)(seqs + (size_t)b * 12800);
        float4* d4 = (float4*)s_seq;
        for (int i = tid; i < n4; i += 256) d4[i] = src4[i];
    }
    __syncthreads();
    int wave = tid >> 6, lane = tid & 63;
    int qA = qbase + wave * 2, qB = qA + 1;
    const float* srA = score + ((size_t)b * 200 + qA) * 200;
    const float* srB = srA + 200;
    float a0 = 0.f, a1 = 0.f, a2 = 0.f, a3 = 0.f;
    float c0 = 0.f, c1 = 0.f, c2 = 0.f, c3 = 0.f;
    int k = 0;
    #pragma unroll 2
    for (; k + 3 <= qA; k += 4) {
        float4 sa = *(const float4*)(srA + k);
        float4 sb = *(const float4*)(srB + k);
        float v0 = s_seq[(k + 0) * 64 + lane];
        float v1 = s_seq[(k + 1) * 64 + lane];
        float v2 = s_seq[(k + 2) * 64 + lane];
        float v3 = s_seq[(k + 3) * 64 + lane];
        a0 += sa.x * v0; a1 += sa.y * v1; a2 += sa.z * v2; a3 += sa.w * v3;
        c0 += sb.x * v0; c1 += sb.y * v1; c2 += sb.z * v2; c3 += sb.w * v3;
    }
    for (; k <= qA; k++) {
        float v = s_seq[k * 64 + lane];
        a0 += srA[k] * v;
        c0 += srB[k] * v;
    }
    c1 += srB[qB] * s_seq[qB * 64 + lane];     // B's extra causal element
    fin[((size_t)b * 200 + qA) * 64 + lane] = (a0 + a1) + (a2 + a3);
    fin[((size_t)b * 200 + qB) * 64 + lane] = (c0 + c1) + (c2 + c3);
}

// R12: FFN/UpDown/logits tail, 2 positions per wave (the proven-good piece of the
// R10/R11 fusion, verified verbatim as k_sff/k_fffn phase 2 in two passing rounds).
// Grid 1600->800: every weight read (LDS + L2) shared by 2 positions, 2x FMA-chain
// ILP in every matvec. 256 threads (R8 lesson: launch_bounds(512) caps VGPR at 128
// and kills load pipelining). VGPR <=144, no spill (measured in R10/R11).
__global__ __launch_bounds__(256) void k_ffn(const float* fin,
                                             const int* poss, const int* negs,
                                             const float* emb,
                                             const float* c1w, const float* c1b,
                                             const float* c2w, const float* c2b,
                                             const float* upw, const float* upb,
                                             const float* gw, const float* gb,
                                             const float* dw, const float* db,
                                             float* out) {
    __shared__ float wl[16384];   // c1w(4096) | c2w(4096) | dw(8192)
    int tid = threadIdx.x;
    {
        float4* l4 = (float4*)wl;
        const float4* a4 = (const float4*)c1w;
        const float4* b4 = (const float4*)c2w;
        const float4* d4 = (const float4*)dw;
        for (int i = tid; i < 1024; i += 256) l4[i] = a4[i];
        for (int i = tid; i < 1024; i += 256) l4[1024 + i] = b4[i];
        for (int i = tid; i < 2048; i += 256) l4[2048 + i] = d4[i];
    }
    __syncthreads();
    int wave = tid >> 6, lane = tid & 63;
    int pA = blockIdx.x * 8 + wave * 2;     // grid 800 -> 6400
    int pB = pA + 1;
    float xA = fin[(size_t)pA * 64 + lane];
    float xB = fin[(size_t)pB * 64 + lane];

    // ---- PointWiseFeedForward ----
    float accA = c1b[lane], accB = c1b[lane];
    #pragma unroll
    for (int kk = 0; kk < 64; kk++) {
        float wv = wl[kk * 64 + lane];
        accA += __shfl(xA, kk, 64) * wv;
        accB += __shfl(xB, kk, 64) * wv;
    }
    float h1A = accA > 0.f ? accA : 0.f;
    float h1B = accB > 0.f ? accB : 0.f;
    accA = c2b[lane]; accB = c2b[lane];
    #pragma unroll
    for (int kk = 0; kk < 64; kk++) {
        float wv = wl[4096 + kk * 64 + lane];
        accA += __shfl(h1A, kk, 64) * wv;
        accB += __shfl(h1B, kk, 64) * wv;
    }
    float x2A = xA + accA;
    float x2B = xB + accB;
    // ---- UpDown ----
    float u0A = upb[lane], u1A = upb[64 + lane];
    float g0A = gb[lane],  g1A = gb[64 + lane];
    float u0B = u0A, u1B = u1A, g0B = g0A, g1B = g1A;
    #pragma unroll
    for (int kk = 0; kk < 64; kk++) {
        float up0 = upw[kk * 128 + lane];
        float up1 = upw[kk * 128 + 64 + lane];
        float gv0 = gw[kk * 128 + lane];
        float gv1 = gw[kk * 128 + 64 + lane];
        float xkA = __shfl(x2A, kk, 64), xkB = __shfl(x2B, kk, 64);
        u0A += xkA * up0; u1A += xkA * up1; g0A += xkA * gv0; g1A += xkA * gv1;
        u0B += xkB * up0; u1B += xkB * up1; g0B += xkB * gv0; g1B += xkB * gv1;
    }
    g0A = g0A > 0.f ? g0A : 0.f;  g1A = g1A > 0.f ? g1A : 0.f;
    g0B = g0B > 0.f ? g0B : 0.f;  g1B = g1B > 0.f ? g1B : 0.f;
    float hh0A = g0A * u0A, hh1A = g1A * u1A;
    float hh0B = g0B * u0B, hh1B = g1B * u1B;
    accA = db[lane]; accB = db[lane];
    #pragma unroll
    for (int kk = 0; kk < 64; kk++) {
        float wv = wl[8192 + kk * 64 + lane];
        accA += __shfl(hh0A, kk, 64) * wv;
        accB += __shfl(hh0B, kk, 64) * wv;
    }
    #pragma unroll
    for (int kk = 0; kk < 64; kk++) {
        float wv = wl[8192 + (64 + kk) * 64 + lane];
        accA += __shfl(hh1A, kk, 64) * wv;
        accB += __shfl(hh1B, kk, 64) * wv;
    }
    float x3A = x2A + (accA > 0.f ? accA : 0.f);
    float x3B = x2B + (accB > 0.f ? accB : 0.f);
    // ---- logits ----
    int pnA = poss[pA], nnA = negs[pA];
    int pnB = poss[pB], nnB = negs[pB];
    float plA = x3A * emb[(size_t)pnA * 64 + lane];
    float nlA = x3A * emb[(size_t)nnA * 64 + lane];
    float plB = x3B * emb[(size_t)pnB * 64 + lane];
    float nlB = x3B * emb[(size_t)nnB * 64 + lane];
    for (int o = 32; o > 0; o >>= 1) {
        plA += __shfl_xor(plA, o, 64);
        nlA += __shfl_xor(nlA, o, 64);
        plB += __shfl_xor(plB, o, 64);
        nlB += __shfl_xor(nlB, o, 64);
    }
    if (lane == 0) {
        out[pA] = plA; out[BLn + pA] = nlA;
        out[pB] = plB; out[BLn + pB] = nlB;
    }
}

extern "C" void kernel_launch(void* const* d_in, const int* in_sizes, int n_in,
                              void* d_out, int out_size, void* d_ws, size_t ws_size,
                              hipStream_t stream) {
    const int* logs = (const int*)d_in[0];
    const int* poss = (const int*)d_in[1];
    const int* negs = (const int*)d_in[2];
    const float* adj      = (const float*)d_in[4];
    const float* item_emb = (const float*)d_in[5];
    const float* posemb   = (const float*)d_in[6];
    const float* W_item   = (const float*)d_in[7];
    const float* a_item   = (const float*)d_in[8];
    const float* W_1      = (const float*)d_in[9];
    const float* W_2      = (const float*)d_in[10];
    const float* b_attn   = (const float*)d_in[11];
    const float* cc       = (const float*)d_in[12];
    const float* cn       = (const float*)d_in[13];
    const float* c1w      = (const float*)d_in[14];
    const float* c1b      = (const float*)d_in[15];
    const float* c2w      = (const float*)d_in[16];
    const float* c2b      = (const float*)d_in[17];
    const float* upw      = (const float*)d_in[18];
    const float* upb      = (const float*)d_in[19];
    const float* gw       = (const float*)d_in[20];
    const float* gb       = (const float*)d_in[21];
    const float* dw       = (const float*)d_in[22];
    const float* db       = (const float*)d_in[23];
    float* out = (float*)d_out;

    float* W = (float*)d_ws;
    size_t off = 0;
    float* h_item = W + off; off += 384064;   // 6001*64
    float* wh1    = W + off; off += 6016;
    float* wh2    = W + off; off += 6016;
    int*   used   = (int*)(W + off); off += 6016;
    float* gat    = W + off; off += 384064;
    float* trans  = W + off; off += 384064;
    float* seqs   = W + off; off += 409600;   // 6400*64
    float* M1     = W + off; off += 409600;   // reused as `final` after k_score
    float* M2T    = W + off; off += 409600;   // [32][64][200]
    float* score  = W + off; off += 1280000;  // [32][200][200]

    k_hitem <<<751, 256, 0, stream>>>(item_emb, W_item, a_item, h_item, wh1, wh2, used);
    k_mark  <<<25, 256, 0, stream>>>(logs, used);
    k_gat   <<<6001, 256, 0, stream>>>(adj, h_item, wh1, wh2, used, gat, trans);
    k_seq   <<<400, 512, 0, stream>>>(logs, gat, trans, item_emb, posemb, cc, cn, W_1, W_2,
                                      seqs, M1, M2T);
    k_score <<<2513, 256, 0, stream>>>(M1, M2T, b_attn, score);
    k_final <<<800, 256, 0, stream>>>(score, seqs, M1);
    k_ffn   <<<800, 256, 0, stream>>>(M1, poss, negs, item_emb,
                                      c1w, c1b, c2w, c2b, upw, upb, gw, gb, dw, db, out);
}

// Round 7
// 373.248 us; speedup vs baseline: 1.0984x; 1.0872x over previous
//
#include <hip/hip_runtime.h>
#include <hip/hip_bf16.h>
#include <cstddef>

#define NP1 6001
#define BLn 6400
#define TRI 20100   // 200*201/2 causal pairs per batch

__global__ __launch_bounds__(256) void k_mark(const int* logs, int* used) {
    int i = blockIdx.x * 256 + threadIdx.x;
    if (i < BLn) used[logs[i]] = 1;
}

// used=0 init folded in; h_item = item_emb @ W_item ; wh1 = h@a[:64] ; wh2 = h@a[64:]
// 8 rows/block (2 per wave, interleaved ILP). Grid 751.
__global__ __launch_bounds__(256) void k_hitem(const float* emb, const float* Wi,
                                               const float* a_item,
                                               float* h, float* wh1, float* wh2, int* used) {
    __shared__ float Wl[4096];
    int tid = threadIdx.x;
    int gid = blockIdx.x * 256 + tid;
    if (gid < NP1) used[gid] = 0;
    {
        const float4* w4 = (const float4*)Wi;
        float4* l4 = (float4*)Wl;
        for (int i = tid; i < 1024; i += 256) l4[i] = w4[i];
    }
    __syncthreads();
    int wave = tid >> 6, lane = tid & 63;
    int rA = blockIdx.x * 8 + wave * 2;
    int rB = rA + 1;
    bool vA = rA < NP1, vB = rB < NP1;
    if (!vA) return;
    float eA = emb[(size_t)rA * 64 + lane];
    float eB = vB ? emb[(size_t)rB * 64 + lane] : 0.f;
    float aA = 0.f, aB = 0.f;
    #pragma unroll
    for (int k = 0; k < 64; k++) {
        float wv = Wl[k * 64 + lane];
        aA += __shfl(eA, k, 64) * wv;
        aB += __shfl(eB, k, 64) * wv;
    }
    h[(size_t)rA * 64 + lane] = aA;
    if (vB) h[(size_t)rB * 64 + lane] = aB;
    float p1A = aA * a_item[lane];
    float p2A = aA * a_item[64 + lane];
    float p1B = aB * a_item[lane];
    float p2B = aB * a_item[64 + lane];
    for (int off = 32; off > 0; off >>= 1) {
        p1A += __shfl_down(p1A, off, 64);
        p2A += __shfl_down(p2A, off, 64);
        p1B += __shfl_down(p1B, off, 64);
        p2B += __shfl_down(p2B, off, 64);
    }
    if (lane == 0) {
        wh1[rA] = p1A; wh2[rA] = p2A;
        if (vB) { wh1[rB] = p1B; wh2[rB] = p2B; }
    }
}

#define MAXNZ 1024
// one block per adjacency row. Pass 1: tight (j,a) compaction scan (pure stream).
// Pass 2: leaky+exp+sum over ~60 compacted nonzeros (inputs ~0.1-scale => |e|<<1,
// softmax safe without max-subtraction). Pass 3: two sparse matvecs.
__global__ __launch_bounds__(256) void k_gat(const float* adj, const float* h,
                                             const float* wh1, const float* wh2,
                                             const int* used, float* gat, float* trans) {
    int row = blockIdx.x;
    if (!used[row]) return;
    __shared__ int s_j[MAXNZ];
    __shared__ float s_a[MAXNZ];
    __shared__ float s_e[MAXNZ];   // exp(e)
    __shared__ int s_cnt;
    __shared__ float s_part[4];
    __shared__ float s_g[4][64];
    __shared__ float s_t[4][64];
    int tid = threadIdx.x;
    if (tid == 0) s_cnt = 0;
    __syncthreads();
    const float* arow = adj + (size_t)row * NP1;

    // row byte alignment: (row*6001) % 4 == row % 4 elements
    int j0 = (4 - (row & 3)) & 3;
    int nv = (NP1 - j0) >> 2;

    for (int j = tid; j < j0; j += 256) {
        float a = arow[j];
        if (a > 0.f) {
            int pos = atomicAdd(&s_cnt, 1);
            if (pos < MAXNZ) { s_j[pos] = j; s_a[pos] = a; }
        }
    }
    const float4* av = (const float4*)(arow + j0);
    for (int v = tid; v < nv; v += 256) {
        float4 a4 = av[v];
        int jb = j0 + 4 * v;
        if (a4.x > 0.f) { int pos = atomicAdd(&s_cnt, 1); if (pos < MAXNZ) { s_j[pos] = jb;     s_a[pos] = a4.x; } }
        if (a4.y > 0.f) { int pos = atomicAdd(&s_cnt, 1); if (pos < MAXNZ) { s_j[pos] = jb + 1; s_a[pos] = a4.y; } }
        if (a4.z > 0.f) { int pos = atomicAdd(&s_cnt, 1); if (pos < MAXNZ) { s_j[pos] = jb + 2; s_a[pos] = a4.z; } }
        if (a4.w > 0.f) { int pos = atomicAdd(&s_cnt, 1); if (pos < MAXNZ) { s_j[pos] = jb + 3; s_a[pos] = a4.w; } }
    }
    for (int j = j0 + 4 * nv + tid; j < NP1; j += 256) {
        float a = arow[j];
        if (a > 0.f) {
            int pos = atomicAdd(&s_cnt, 1);
            if (pos < MAXNZ) { s_j[pos] = j; s_a[pos] = a; }
        }
    }
    __syncthreads();
    int cnt = min(s_cnt, MAXNZ);
    float w1 = wh1[row];
    float ssum = 0.f;
    for (int i = tid; i < cnt; i += 256) {
        float e = w1 + wh2[s_j[i]];
        e = e > 0.f ? e : 0.01f * e;
        float ee = __expf(e);
        s_e[i] = ee;
        ssum += ee;
    }
    int lane = tid & 63, g = tid >> 6;
    for (int o = 32; o > 0; o >>= 1) ssum += __shfl_xor(ssum, o, 64);
    if (lane == 0) s_part[g] = ssum;
    __syncthreads();
    float inv = __builtin_amdgcn_rcpf(s_part[0] + s_part[1] + s_part[2] + s_part[3]);
    float gacc = 0.f, tacc = 0.f;
    for (int i = g; i < cnt; i += 4) {
        int j = s_j[i];
        float hv = h[(size_t)j * 64 + lane];
        gacc += s_e[i] * hv;
        tacc += s_a[i] * hv;
    }
    s_g[g][lane] = gacc * inv;
    s_t[g][lane] = tacc;
    __syncthreads();
    if (g == 0) {
        gat[(size_t)row * 64 + lane]   = s_g[0][lane] + s_g[1][lane] + s_g[2][lane] + s_g[3][lane];
        trans[(size_t)row * 64 + lane] = s_t[0][lane] + s_t[1][lane] + s_t[2][lane] + s_t[3][lane];
    }
}

// seqs = coff*gat + (1-coff)*trans + self ; M1 = seqs_pos@W1 ; M2T[b][d][l] = (seqs_pos@W2)[d]
// 512 threads, full LDS staging, 2 positions/wave interleaved.
__global__ __launch_bounds__(512) void k_seq(const int* logs, const float* gat, const float* trans,
                                             const float* emb, const float* posemb,
                                             const float* cc_, const float* cn_,
                                             const float* W1_, const float* W2_,
                                             float* seqs, float* M1, float* M2T) {
    __shared__ float cc[4096], cn[4096], W1[4096], W2[4096];
    int tid = threadIdx.x;
    {
        float4* c4 = (float4*)cc; float4* n4 = (float4*)cn;
        float4* w14 = (float4*)W1; float4* w24 = (float4*)W2;
        const float4* sc = (const float4*)cc_; const float4* sn = (const float4*)cn_;
        const float4* s1 = (const float4*)W1_; const float4* s2 = (const float4*)W2_;
        for (int i = tid; i < 1024; i += 512) {
            c4[i] = sc[i]; n4[i] = sn[i]; w14[i] = s1[i]; w24[i] = s2[i];
        }
    }
    __syncthreads();
    int wave = tid >> 6, lane = tid & 63;
    int pA = blockIdx.x * 16 + wave * 2;     // grid 400 -> 6400 positions
    int pB = pA + 1;
    int bA = pA / 200, lA = pA - bA * 200;
    int bB = pB / 200, lB = pB - bB * 200;
    int nA = logs[pA], nB = logs[pB];
    float gA = gat[(size_t)nA * 64 + lane];
    float gB = gat[(size_t)nB * 64 + lane];
    float tA = trans[(size_t)nA * 64 + lane];
    float tB = trans[(size_t)nB * 64 + lane];
    float seA = emb[(size_t)nA * 64 + lane];
    float seB = emb[(size_t)nB * 64 + lane];
    float ciA = 0.f, ciB = 0.f;
    #pragma unroll
    for (int k = 0; k < 64; k++) {
        float ccv = cc[k * 64 + lane], cnv = cn[k * 64 + lane];
        ciA += __shfl(gA, k, 64) * ccv + __shfl(tA, k, 64) * cnv;
        ciB += __shfl(gB, k, 64) * ccv + __shfl(tB, k, 64) * cnv;
    }
    float coA = 1.f / (1.f + __expf(-ciA));
    float coB = 1.f / (1.f + __expf(-ciB));
    float sA = coA * gA + (1.f - coA) * tA + seA;
    float sB = coB * gB + (1.f - coB) * tB + seB;
    seqs[(size_t)pA * 64 + lane] = sA;
    seqs[(size_t)pB * 64 + lane] = sB;
    float spA = sA + (nA != 0 ? posemb[lA * 64 + lane] : 0.f);
    float spB = sB + (nB != 0 ? posemb[lB * 64 + lane] : 0.f);
    float m1A = 0.f, m2A = 0.f, m1B = 0.f, m2B = 0.f;
    #pragma unroll
    for (int k = 0; k < 64; k++) {
        float w1v = W1[k * 64 + lane], w2v = W2[k * 64 + lane];
        float skA = __shfl(spA, k, 64), skB = __shfl(spB, k, 64);
        m1A += skA * w1v; m2A += skA * w2v;
        m1B += skB * w1v; m2B += skB * w2v;
    }
    M1[(size_t)pA * 64 + lane] = m1A;
    M1[(size_t)pB * 64 + lane] = m1B;
    M2T[((size_t)bA * 64 + lane) * 200 + lA] = m2A;
    M2T[((size_t)bB * 64 + lane) * 200 + lB] = m2B;
}

// score[b,q,k] = sum_d sigmoid(M1[b,q,d]+M2[b,k,d]) * b_attn[d]; causal triples only.
// R10/R11 lesson: keep this standalone — the flat idx->triangle map distributes the
// triangular work evenly over 643K threads; any per-block fusion serializes it.
__global__ __launch_bounds__(256) void k_score(const float* M1, const float* M2T,
                                               const float* battn, float* score) {
    __shared__ float bv[64];
    int tid = threadIdx.x;
    if (tid < 64) bv[tid] = battn[tid];
    __syncthreads();
    int idx = blockIdx.x * 256 + tid;          // grid 2513 -> 643,328 (need 643,200)
    if (idx >= TRI * 32) return;
    int b = idx / TRI;
    int t = idx - b * TRI;
    int q = (int)((sqrtf(8.0f * (float)t + 1.0f) - 1.0f) * 0.5f);
    while ((q + 1) * (q + 2) / 2 <= t) q++;
    while (q * (q + 1) / 2 > t) q--;
    int k = t - q * (q + 1) / 2;
    const float4* m14 = (const float4*)(M1 + ((size_t)(b * 200 + q)) * 64);
    const float* m2 = M2T + (size_t)b * 12800 + k;
    float s0 = 0.f, s1 = 0.f, s2 = 0.f, s3 = 0.f;
    #pragma unroll
    for (int d4 = 0; d4 < 16; d4++) {
        float4 mv = m14[d4];
        int d = d4 * 4;
        float x0 = mv.x + m2[(size_t)(d + 0) * 200];
        float x1 = mv.y + m2[(size_t)(d + 1) * 200];
        float x2 = mv.z + m2[(size_t)(d + 2) * 200];
        float x3 = mv.w + m2[(size_t)(d + 3) * 200];
        s0 += bv[d + 0] * __builtin_amdgcn_rcpf(1.0f + __expf(-x0));
        s1 += bv[d + 1] * __builtin_amdgcn_rcpf(1.0f + __expf(-x1));
        s2 += bv[d + 2] * __builtin_amdgcn_rcpf(1.0f + __expf(-x2));
        s3 += bv[d + 3] * __builtin_amdgcn_rcpf(1.0f + __expf(-x3));
    }
    score[((size_t)(b * 200 + q)) * 200 + k] = (s0 + s1) + (s2 + s3);
}

// final[b,q,:] = sum_{k<=q} score[b,q,k] * seqs[b,k,:], seqs[b] prefix in LDS
// (51.2KB max -> 3 blocks/CU). Block = (batch b, 8 consecutive q), grid 800.
// Wave handles 2 adjacent q sharing every ds_read (2-way aliasing = free).
// Output into M1's slot (dead after k_score). R11 lesson: do NOT fuse the FFN tail
// behind this block's barrier (64KB arena -> 2 blocks/CU + triangular tail = 102us).
__global__ __launch_bounds__(256) void k_final(const float* score, const float* seqs,
                                               float* fin) {
    __shared__ float s_seq[12800];
    int tid = threadIdx.x;
    int B = blockIdx.x;
    int b = B / 25;
    int qbase = (B - b * 25) * 8;
    int kmax = qbase + 7;                      // rows 0..kmax of seqs[b] needed
    {
        int n4 = (kmax + 1) * 16;              // float4 count
        const float4* src4 = (const float4*)(seqs + (size_t)b * 12800);
        float4* d4 = (float4*)s_seq;
        for (int i = tid; i < n4; i += 256) d4[i] = src4[i];
    }
    __syncthreads();
    int wave = tid >> 6, lane = tid & 63;
    int qA = qbase + wave * 2, qB = qA + 1;
    const float* srA = score + ((size_t)b * 200 + qA) * 200;
    const float* srB = srA + 200;
    float a0 = 0.f, a1 = 0.f, a2 = 0.f, a3 = 0.f;
    float c0 = 0.f, c1 = 0.f, c2 = 0.f, c3 = 0.f;
    int k = 0;
    #pragma unroll 2
    for (; k + 3 <= qA; k += 4) {
        float4 sa = *(const float4*)(srA + k);
        float4 sb = *(const float4*)(srB + k);
        float v0 = s_seq[(k + 0) * 64 + lane];
        float v1 = s_seq[(k + 1) * 64 + lane];
        float v2 = s_seq[(k + 2) * 64 + lane];
        float v3 = s_seq[(k + 3) * 64 + lane];
        a0 += sa.x * v0; a1 += sa.y * v1; a2 += sa.z * v2; a3 += sa.w * v3;
        c0 += sb.x * v0; c1 += sb.y * v1; c2 += sb.z * v2; c3 += sb.w * v3;
    }
    for (; k <= qA; k++) {
        float v = s_seq[k * 64 + lane];
        a0 += srA[k] * v;
        c0 += srB[k] * v;
    }
    c1 += srB[qB] * s_seq[qB * 64 + lane];     // B's extra causal element
    fin[((size_t)b * 200 + qA) * 64 + lane] = (a0 + a1) + (a2 + a3);
    fin[((size_t)b * 200 + qB) * 64 + lane] = (c0 + c1) + (c2 + c3);
}

// FFN/UpDown/logits tail. Known-good R9 config: 256 threads, wave-per-position,
// grid 1600, c1w/c2w/dw in LDS, upw/gw from L2.
// NOTE (R6 lesson): 1 position per wave — doubling accumulator state spilled at 256 VGPR.
// NOTE (R8 lesson): __launch_bounds__(512) halves the VGPR budget — avoid here.
// NOTE (R12 lesson): 2-pos/wave @ grid 800 measured no better (within noise); this
// exact config holds the best measured total (376 us).
__global__ __launch_bounds__(256) void k_ffn(const float* fin,
                                             const int* poss, const int* negs,
                                             const float* emb,
                                             const float* c1w, const float* c1b,
                                             const float* c2w, const float* c2b,
                                             const float* upw, const float* upb,
                                             const float* gw, const float* gb,
                                             const float* dw, const float* db,
                                             float* out) {
    __shared__ float wl[16384];   // c1w(4096) | c2w(4096) | dw(8192)
    int tid = threadIdx.x;
    {
        float4* l4 = (float4*)wl;
        const float4* a4 = (const float4*)c1w;
        const float4* b4 = (const float4*)c2w;
        const float4* d4 = (const float4*)dw;
        for (int i = tid; i < 1024; i += 256) l4[i] = a4[i];
        for (int i = tid; i < 1024; i += 256) l4[1024 + i] = b4[i];
        for (int i = tid; i < 2048; i += 256) l4[2048 + i] = d4[i];
    }
    __syncthreads();
    int wave = tid >> 6, lane = tid & 63;
    int p = blockIdx.x * 4 + wave;          // grid 1600 -> 6400
    float x = fin[(size_t)p * 64 + lane];

    // ---- PointWiseFeedForward ----
    float acc = c1b[lane];
    #pragma unroll
    for (int kk = 0; kk < 64; kk++) acc += __shfl(x, kk, 64) * wl[kk * 64 + lane];
    float h1 = acc > 0.f ? acc : 0.f;
    acc = c2b[lane];
    #pragma unroll
    for (int kk = 0; kk < 64; kk++) acc += __shfl(h1, kk, 64) * wl[4096 + kk * 64 + lane];
    float x2 = x + acc;
    // ---- UpDown ----
    float u0 = upb[lane], u1 = upb[64 + lane];
    float g0 = gb[lane],  g1 = gb[64 + lane];
    #pragma unroll
    for (int kk = 0; kk < 64; kk++) {
        float xk = __shfl(x2, kk, 64);
        u0 += xk * upw[kk * 128 + lane];
        u1 += xk * upw[kk * 128 + 64 + lane];
        g0 += xk * gw[kk * 128 + lane];
        g1 += xk * gw[kk * 128 + 64 + lane];
    }
    g0 = g0 > 0.f ? g0 : 0.f;
    g1 = g1 > 0.f ? g1 : 0.f;
    float hh0 = g0 * u0, hh1 = g1 * u1;
    acc = db[lane];
    #pragma unroll
    for (int kk = 0; kk < 64; kk++) acc += __shfl(hh0, kk, 64) * wl[8192 + kk * 64 + lane];
    #pragma unroll
    for (int kk = 0; kk < 64; kk++) acc += __shfl(hh1, kk, 64) * wl[8192 + (64 + kk) * 64 + lane];
    float x3 = x2 + (acc > 0.f ? acc : 0.f);
    // ---- logits ----
    int pn = poss[p], nn = negs[p];
    float pl = x3 * emb[(size_t)pn * 64 + lane];
    float nl = x3 * emb[(size_t)nn * 64 + lane];
    for (int o = 32; o > 0; o >>= 1) {
        pl += __shfl_xor(pl, o, 64);
        nl += __shfl_xor(nl, o, 64);
    }
    if (lane == 0) { out[p] = pl; out[BLn + p] = nl; }
}

extern "C" void kernel_launch(void* const* d_in, const int* in_sizes, int n_in,
                              void* d_out, int out_size, void* d_ws, size_t ws_size,
                              hipStream_t stream) {
    const int* logs = (const int*)d_in[0];
    const int* poss = (const int*)d_in[1];
    const int* negs = (const int*)d_in[2];
    const float* adj      = (const float*)d_in[4];
    const float* item_emb = (const float*)d_in[5];
    const float* posemb   = (const float*)d_in[6];
    const float* W_item   = (const float*)d_in[7];
    const float* a_item   = (const float*)d_in[8];
    const float* W_1      = (const float*)d_in[9];
    const float* W_2      = (const float*)d_in[10];
    const float* b_attn   = (const float*)d_in[11];
    const float* cc       = (const float*)d_in[12];
    const float* cn       = (const float*)d_in[13];
    const float* c1w      = (const float*)d_in[14];
    const float* c1b      = (const float*)d_in[15];
    const float* c2w      = (const float*)d_in[16];
    const float* c2b      = (const float*)d_in[17];
    const float* upw      = (const float*)d_in[18];
    const float* upb      = (const float*)d_in[19];
    const float* gw       = (const float*)d_in[20];
    const float* gb       = (const float*)d_in[21];
    const float* dw       = (const float*)d_in[22];
    const float* db       = (const float*)d_in[23];
    float* out = (float*)d_out;

    float* W = (float*)d_ws;
    size_t off = 0;
    float* h_item = W + off; off += 384064;   // 6001*64
    float* wh1    = W + off; off += 6016;
    float* wh2    = W + off; off += 6016;
    int*   used   = (int*)(W + off); off += 6016;
    float* gat    = W + off; off += 384064;
    float* trans  = W + off; off += 384064;
    float* seqs   = W + off; off += 409600;   // 6400*64
    float* M1     = W + off; off += 409600;   // reused as `final` after k_score
    float* M2T    = W + off; off += 409600;   // [32][64][200]
    float* score  = W + off; off += 1280000;  // [32][200][200]

    k_hitem <<<751, 256, 0, stream>>>(item_emb, W_item, a_item, h_item, wh1, wh2, used);
    k_mark  <<<25, 256, 0, stream>>>(logs, used);
    k_gat   <<<6001, 256, 0, stream>>>(adj, h_item, wh1, wh2, used, gat, trans);
    k_seq   <<<400, 512, 0, stream>>>(logs, gat, trans, item_emb, posemb, cc, cn, W_1, W_2,
                                      seqs, M1, M2T);
    k_score <<<2513, 256, 0, stream>>>(M1, M2T, b_attn, score);
    k_final <<<800, 256, 0, stream>>>(score, seqs, M1);
    k_ffn   <<<1600, 256, 0, stream>>>(M1, poss, negs, item_emb,
                                       c1w, c1b, c2w, c2b, upw, upb, gw, gb, dw, db, out);
}